// Round 5
// baseline (485.885 us; speedup 1.0000x reference)
//
#include <hip/hip_runtime.h>

#define BB 8
#define NN 256
#define FF 64
#define T0  4   // tiles per block, edge0
#define T12 4   // tiles per block, edge12 (must divide 512 so b is block-constant)
#define E2S 72  // E2 row stride in u16 (16B aligned, decorrelates banks)

typedef float f32x4 __attribute__((ext_vector_type(4)));
typedef short s16x8 __attribute__((ext_vector_type(8)));
typedef unsigned short u16;

#define MFMA_BF16(a, b, c) __builtin_amdgcn_mfma_f32_16x16x32_bf16(a, b, c, 0, 0, 0)

__device__ inline u16 f2bf(float x) {
    unsigned u = __float_as_uint(x);
    u += 0x7FFFu + ((u >> 16) & 1u);
    return (u16)(u >> 16);
}
__device__ inline float bf2f(u16 h) { return __uint_as_float(((unsigned)h) << 16); }

__device__ inline s16x8 cvt8(f32x4 a, f32x4 b) {
    s16x8 r;
    r[0] = (short)f2bf(a[0]); r[1] = (short)f2bf(a[1]);
    r[2] = (short)f2bf(a[2]); r[3] = (short)f2bf(a[3]);
    r[4] = (short)f2bf(b[0]); r[5] = (short)f2bf(b[1]);
    r[6] = (short)f2bf(b[2]); r[7] = (short)f2bf(b[3]);
    return r;
}

// ---------------------------------------------------------------------------
// pq (+ fused wprep): P[r]=be+x[r]@We[0:64], Q[r]=x[r]@We[64:128]; zero agg.
// Blocks 0..2 additionally build the W-MFMA images for layers 0..2:
// image[f*64 + cs*8 + j] = W[k=( (cs^(f&7))<<3 | j )][f], hi/lo bf16 split.
// ---------------------------------------------------------------------------
__global__ __launch_bounds__(256) void pq_kernel(
    const float* __restrict__ x, const float* __restrict__ We,
    const float* __restrict__ be, float* __restrict__ P, float* __restrict__ Q,
    float* __restrict__ agg,
    const float* __restrict__ We0, const float* __restrict__ We1,
    const float* __restrict__ We2, u16* __restrict__ wimg)
{
    const int rl = threadIdx.x >> 6, f = threadIdx.x & 63;
    const int r = blockIdx.x * 4 + rl;
    __shared__ float xs[4][FF];
    xs[rl][f] = x[r * FF + f];
    agg[r * FF + f] = 0.f;

    if (blockIdx.x < 3) {  // wprep for layer blockIdx.x
        const float* src =
            (blockIdx.x == 0 ? We0 : (blockIdx.x == 1 ? We1 : We2)) + 2 * FF * FF;
        u16* hi = wimg + blockIdx.x * 8192;
        u16* lo = hi + 4096;
        for (int idx = threadIdx.x; idx < 4096; idx += 256) {
            const int ff = idx >> 6, rem = idx & 63, cs = rem >> 3, j = rem & 7;
            const int k = ((cs ^ (ff & 7)) << 3) | j;
            const float wv = src[k * FF + ff];
            const u16 h = f2bf(wv);
            hi[idx] = h;
            lo[idx] = f2bf(wv - bf2f(h));
        }
    }
    __syncthreads();
    float p = be[f], q = 0.f;
#pragma unroll
    for (int k = 0; k < FF; ++k) {
        const float xv = xs[rl][k];
        p = fmaf(xv, We[k * FF + f], p);
        q = fmaf(xv, We[(FF + k) * FF + f], q);
    }
    P[r * FF + f] = p;
    Q[r * FF + f] = q;
}

// ---------------------------------------------------------------------------
// edge0 (MFMA, transposed: D[f][e] = Wc^T E^T). T0 tiles/block, no per-tile
// barriers. Lane holds f = 16ft+4quad+r (contiguous over r), e = 32w+16et+l15.
// Writes e1 as packed bf16 into the FIRST HALF of each fp32 e_attr row
// (u16 row stride 128); row reads complete (MFMA data-dep) before its store.
// ---------------------------------------------------------------------------
__global__ __launch_bounds__(256) void edge0_kernel(
    const float* __restrict__ e_in, u16* __restrict__ e1_out,
    const u16* __restrict__ wimg, const float* __restrict__ P,
    const float* __restrict__ Q, const int* __restrict__ Adj,
    float* __restrict__ agg)
{
    __shared__ u16 Wh[4096], Wl[4096];
    const int tid = threadIdx.x;
#pragma unroll
    for (int m = 0; m < 2; ++m) {
        ((uint4*)Wh)[tid + 256 * m] = ((const uint4*)wimg)[tid + 256 * m];
        ((uint4*)Wl)[tid + 256 * m] = ((const uint4*)(wimg + 4096))[tid + 256 * m];
    }
    __syncthreads();

    const int w = tid >> 6, lane = tid & 63;
    const int quad = lane >> 4, l15 = lane & 15, l7 = lane & 7;
    const int e0 = 32 * w + l15;

#pragma unroll
    for (int tt = 0; tt < T0; ++tt) {
        const int bt = blockIdx.x * T0 + tt;
        const int bi = bt >> 1, b = bi >> 8;
        const int j0 = (bt & 1) << 7;

        // E B-frags: E[e][k = ks*32 + quad*8 + j], fp32 -> bf16
        f32x4 ef[2][2][2];
        const float* erow = e_in + ((size_t)bi * NN + j0) * FF;
#pragma unroll
        for (int ks = 0; ks < 2; ++ks)
#pragma unroll
            for (int et = 0; et < 2; ++et) {
                const float* p = erow + (size_t)(e0 + 16 * et) * FF + ks * 32 + quad * 8;
                ef[ks][et][0] = *(const f32x4*)p;
                ef[ks][et][1] = *(const f32x4*)(p + 4);
            }

        float av[2];
#pragma unroll
        for (int et = 0; et < 2; ++et)
            av[et] = (float)Adj[bi * NN + j0 + e0 + 16 * et];
        f32x4 pv[4];
#pragma unroll
        for (int ft = 0; ft < 4; ++ft)
            pv[ft] = *(const f32x4*)(P + bi * FF + ft * 16 + quad * 4);
        f32x4 qv[2][4];
        const float* Qb = Q + ((size_t)b * NN + j0) * FF;
#pragma unroll
        for (int et = 0; et < 2; ++et)
#pragma unroll
            for (int ft = 0; ft < 4; ++ft)
                qv[et][ft] = *(const f32x4*)(Qb + (size_t)(e0 + 16 * et) * FF +
                                             ft * 16 + quad * 4);

        f32x4 acc[2][4];
#pragma unroll
        for (int et = 0; et < 2; ++et)
#pragma unroll
            for (int ft = 0; ft < 4; ++ft) acc[et][ft] = (f32x4){0.f, 0.f, 0.f, 0.f};

#pragma unroll
        for (int ks = 0; ks < 2; ++ks) {
            s16x8 efr[2];
#pragma unroll
            for (int et = 0; et < 2; ++et) efr[et] = cvt8(ef[ks][et][0], ef[ks][et][1]);
#pragma unroll
            for (int ft = 0; ft < 4; ++ft) {
                const int off = (16 * ft + l15) * 64 + (((ks * 4 + quad) ^ l7) << 3);
                const s16x8 ah = *(const s16x8*)&Wh[off];
                const s16x8 al = *(const s16x8*)&Wl[off];
#pragma unroll
                for (int et = 0; et < 2; ++et) {
                    acc[et][ft] = MFMA_BF16(ah, efr[et], acc[et][ft]);
                    acc[et][ft] = MFMA_BF16(al, efr[et], acc[et][ft]);
                }
            }
        }

        // epilogue: relu(acc + P[f] + Q[e][f]) * A[e]; store bf16x4; row-sum
        float sac[4][4];
#pragma unroll
        for (int ft = 0; ft < 4; ++ft)
#pragma unroll
            for (int r = 0; r < 4; ++r) sac[ft][r] = 0.f;
#pragma unroll
        for (int et = 0; et < 2; ++et) {
            const size_t erow_g = (size_t)bi * NN + j0 + e0 + 16 * et;
#pragma unroll
            for (int ft = 0; ft < 4; ++ft) {
                float rr[4];
#pragma unroll
                for (int r = 0; r < 4; ++r) {
                    const float val = acc[et][ft][r] + pv[ft][r] + qv[et][ft][r];
                    rr[r] = fmaxf(val, 0.f) * av[et];
                    sac[ft][r] += rr[r];
                }
                ushort4 st;
                st.x = f2bf(rr[0]); st.y = f2bf(rr[1]);
                st.z = f2bf(rr[2]); st.w = f2bf(rr[3]);
                *(ushort4*)(e1_out + erow_g * 128 + ft * 16 + quad * 4) = st;
            }
        }
#pragma unroll
        for (int ft = 0; ft < 4; ++ft)
#pragma unroll
            for (int r = 0; r < 4; ++r) {
                float s = sac[ft][r];
                s += __shfl_xor(s, 1, 16);
                s += __shfl_xor(s, 2, 16);
                s += __shfl_xor(s, 4, 16);
                s += __shfl_xor(s, 8, 16);
                if (l15 == 0)
                    atomicAdd(&agg[bi * FF + ft * 16 + quad * 4 + r], s);
            }
    }
}

// ---------------------------------------------------------------------------
// fused node-update + deg + pq(1,2) + zero v.
// ---------------------------------------------------------------------------
__global__ __launch_bounds__(256) void nodepq_kernel(
    const float* __restrict__ x, const float* __restrict__ agg,
    const int* __restrict__ A,
    const float* __restrict__ Wn, const float* __restrict__ bn,
    const float* __restrict__ We1, const float* __restrict__ be1,
    const float* __restrict__ We2, const float* __restrict__ be2,
    float* __restrict__ P1, float* __restrict__ Q1,
    float* __restrict__ P2, float* __restrict__ Q2, float* __restrict__ v)
{
    const int rl = threadIdx.x >> 6, f = threadIdx.x & 63;
    const int r = blockIdx.x * 4 + rl;
    __shared__ float s[4][2 * FF];
    __shared__ float x1s[4][FF];

    float da = (float)A[r * NN + f] + (float)A[r * NN + f + 64] +
               (float)A[r * NN + f + 128] + (float)A[r * NN + f + 192];
#pragma unroll
    for (int off = 32; off > 0; off >>= 1) da += __shfl_down(da, off, 64);
    const float deg = fmaxf(__shfl(da, 0, 64), 1.0f);

    s[rl][f]      = x[r * FF + f];
    s[rl][FF + f] = agg[r * FF + f] / deg;
    if (blockIdx.x == 0) {
        v[threadIdx.x] = 0.f;
        v[256 + threadIdx.x] = 0.f;
    }
    __syncthreads();
    float a = bn[f];
#pragma unroll
    for (int k = 0; k < 2 * FF; ++k) a = fmaf(s[rl][k], Wn[k * FF + f], a);
    x1s[rl][f] = fmaxf(a, 0.f);
    __syncthreads();
    float p1 = be1[f], q1 = 0.f, p2 = be2[f], q2 = 0.f;
#pragma unroll
    for (int k = 0; k < FF; ++k) {
        const float xv = x1s[rl][k];
        p1 = fmaf(xv, We1[k * FF + f], p1);
        q1 = fmaf(xv, We1[(FF + k) * FF + f], q1);
        p2 = fmaf(xv, We2[k * FF + f], p2);
        q2 = fmaf(xv, We2[(FF + k) * FF + f], q2);
    }
    P1[r * FF + f] = p1;  Q1[r * FF + f] = q1;
    P2[r * FF + f] = p2;  Q2[r * FF + f] = q2;
}

// ---------------------------------------------------------------------------
// fused layers 1+2 (MFMA, transposed). T12 tiles/block, barrier-free tile
// loop: e2 round-trips through a WAVE-PRIVATE LDS image (rows e owned and
// consumed by the same wave). e1 read as packed bf16 (stride-128 u16 rows).
// v accumulated in registers across tiles, one atomic flush per block.
// ---------------------------------------------------------------------------
__global__ __launch_bounds__(256) void edge12_kernel(
    const u16* __restrict__ e1,
    const u16* __restrict__ w1img, const u16* __restrict__ w2img,
    const float* __restrict__ P1, const float* __restrict__ Q1,
    const float* __restrict__ P2, const float* __restrict__ Q2,
    const int* __restrict__ Adj, float* __restrict__ v)
{
    __shared__ u16 W1h[4096], W1l[4096], W2h[4096], W2l[4096];
    __shared__ u16 E2[4][32 * E2S];
    const int tid = threadIdx.x;
#pragma unroll
    for (int m = 0; m < 2; ++m) {
        ((uint4*)W1h)[tid + 256 * m] = ((const uint4*)w1img)[tid + 256 * m];
        ((uint4*)W1l)[tid + 256 * m] = ((const uint4*)(w1img + 4096))[tid + 256 * m];
        ((uint4*)W2h)[tid + 256 * m] = ((const uint4*)w2img)[tid + 256 * m];
        ((uint4*)W2l)[tid + 256 * m] = ((const uint4*)(w2img + 4096))[tid + 256 * m];
    }
    __syncthreads();

    const int w = tid >> 6, lane = tid & 63;
    const int quad = lane >> 4, l15 = lane & 15, l7 = lane & 7;
    const int e0 = 32 * w + l15;
    u16* E2w = E2[w];
    const int b = (blockIdx.x * T12) >> 9;  // constant within block (T12 | 512)

    float vac[4][4];
#pragma unroll
    for (int ft = 0; ft < 4; ++ft)
#pragma unroll
        for (int r = 0; r < 4; ++r) vac[ft][r] = 0.f;

#pragma unroll
    for (int tt = 0; tt < T12; ++tt) {
        const int bt = blockIdx.x * T12 + tt;
        const int bi = bt >> 1;
        const int j0 = (bt & 1) << 7;

        // e1 B-frags (bf16 direct)
        s16x8 bfr[2][2];
#pragma unroll
        for (int ks = 0; ks < 2; ++ks)
#pragma unroll
            for (int et = 0; et < 2; ++et)
                bfr[ks][et] = *(const s16x8*)(e1 +
                    ((size_t)bi * NN + j0 + e0 + 16 * et) * 128 + ks * 32 + quad * 8);

        float av[2];
#pragma unroll
        for (int et = 0; et < 2; ++et)
            av[et] = (float)Adj[bi * NN + j0 + e0 + 16 * et];
        f32x4 pv[4];
#pragma unroll
        for (int ft = 0; ft < 4; ++ft)
            pv[ft] = *(const f32x4*)(P1 + bi * FF + ft * 16 + quad * 4);
        f32x4 qv[2][4];
        const float* Q1b = Q1 + ((size_t)b * NN + j0) * FF;
#pragma unroll
        for (int et = 0; et < 2; ++et)
#pragma unroll
            for (int ft = 0; ft < 4; ++ft)
                qv[et][ft] = *(const f32x4*)(Q1b + (size_t)(e0 + 16 * et) * FF +
                                             ft * 16 + quad * 4);

        // ---------------- GEMM1 ----------------
        f32x4 acc[2][4];
#pragma unroll
        for (int et = 0; et < 2; ++et)
#pragma unroll
            for (int ft = 0; ft < 4; ++ft) acc[et][ft] = (f32x4){0.f, 0.f, 0.f, 0.f};
#pragma unroll
        for (int ks = 0; ks < 2; ++ks)
#pragma unroll
            for (int ft = 0; ft < 4; ++ft) {
                const int off = (16 * ft + l15) * 64 + (((ks * 4 + quad) ^ l7) << 3);
                const s16x8 ah = *(const s16x8*)&W1h[off];
                const s16x8 al = *(const s16x8*)&W1l[off];
#pragma unroll
                for (int et = 0; et < 2; ++et) {
                    acc[et][ft] = MFMA_BF16(ah, bfr[ks][et], acc[et][ft]);
                    acc[et][ft] = MFMA_BF16(al, bfr[ks][et], acc[et][ft]);
                }
            }

        // epilogue 1 -> wave-private E2 image [e_local][f], stride E2S
#pragma unroll
        for (int et = 0; et < 2; ++et) {
            const int erow_l = (16 * et + l15) * E2S;
#pragma unroll
            for (int ft = 0; ft < 4; ++ft) {
                float rr[4];
#pragma unroll
                for (int r = 0; r < 4; ++r) {
                    const float val = acc[et][ft][r] + pv[ft][r] + qv[et][ft][r];
                    rr[r] = fmaxf(val, 0.f) * av[et];
                }
                ushort4 st;
                st.x = f2bf(rr[0]); st.y = f2bf(rr[1]);
                st.z = f2bf(rr[2]); st.w = f2bf(rr[3]);
                *(ushort4*)&E2w[erow_l + ft * 16 + quad * 4] = st;
            }
        }

        // P2/Q2 for epilogue 2
#pragma unroll
        for (int ft = 0; ft < 4; ++ft)
            pv[ft] = *(const f32x4*)(P2 + bi * FF + ft * 16 + quad * 4);
        const float* Q2b = Q2 + ((size_t)b * NN + j0) * FF;
#pragma unroll
        for (int et = 0; et < 2; ++et)
#pragma unroll
            for (int ft = 0; ft < 4; ++ft)
                qv[et][ft] = *(const f32x4*)(Q2b + (size_t)(e0 + 16 * et) * FF +
                                             ft * 16 + quad * 4);

        // ---------------- GEMM2 (no barrier: E2 rows are wave-private) ----
#pragma unroll
        for (int et = 0; et < 2; ++et)
#pragma unroll
            for (int ft = 0; ft < 4; ++ft) acc[et][ft] = (f32x4){0.f, 0.f, 0.f, 0.f};
#pragma unroll
        for (int ks = 0; ks < 2; ++ks) {
            s16x8 e2f[2];
#pragma unroll
            for (int et = 0; et < 2; ++et)
                e2f[et] = *(const s16x8*)&E2w[(16 * et + l15) * E2S + ks * 32 + quad * 8];
#pragma unroll
            for (int ft = 0; ft < 4; ++ft) {
                const int off = (16 * ft + l15) * 64 + (((ks * 4 + quad) ^ l7) << 3);
                const s16x8 ah = *(const s16x8*)&W2h[off];
                const s16x8 al = *(const s16x8*)&W2l[off];
#pragma unroll
                for (int et = 0; et < 2; ++et) {
                    acc[et][ft] = MFMA_BF16(ah, e2f[et], acc[et][ft]);
                    acc[et][ft] = MFMA_BF16(al, e2f[et], acc[et][ft]);
                }
            }
        }

        // epilogue 2: accumulate relu(acc + P2 + Q2)*A into vac
#pragma unroll
        for (int et = 0; et < 2; ++et)
#pragma unroll
            for (int ft = 0; ft < 4; ++ft)
#pragma unroll
                for (int r = 0; r < 4; ++r) {
                    const float val = acc[et][ft][r] + pv[ft][r] + qv[et][ft][r];
                    vac[ft][r] += fmaxf(val, 0.f) * av[et];
                }
    }

    // flush v: reduce over l15 (16 e per quad-group), atomic from l15==0 lanes
#pragma unroll
    for (int ft = 0; ft < 4; ++ft)
#pragma unroll
        for (int r = 0; r < 4; ++r) {
            float s = vac[ft][r];
            s += __shfl_xor(s, 1, 16);
            s += __shfl_xor(s, 2, 16);
            s += __shfl_xor(s, 4, 16);
            s += __shfl_xor(s, 8, 16);
            if (l15 == 0)
                atomicAdd(&v[b * FF + ft * 16 + quad * 4 + r], s);
        }
}

// ---------------------------------------------------------------------------
// head: v/65536 -> relu(@W1+b1) -> relu(@W2+b2) -> @W3+b3
// ---------------------------------------------------------------------------
__global__ __launch_bounds__(64) void head_kernel(
    const float* __restrict__ vsum, const float* __restrict__ W1,
    const float* __restrict__ b1, const float* __restrict__ W2,
    const float* __restrict__ b2, const float* __restrict__ W3,
    const float* __restrict__ b3, float* __restrict__ out)
{
    const int f = threadIdx.x;
    __shared__ float hv[BB][FF];
    __shared__ float h1[BB][FF];
#pragma unroll
    for (int b = 0; b < BB; ++b) hv[b][f] = vsum[b * FF + f] * (1.0f / 65536.0f);
    __syncthreads();
#pragma unroll
    for (int b = 0; b < BB; ++b) {
        float acc = b1[f];
#pragma unroll
        for (int k = 0; k < FF; ++k) acc = fmaf(hv[b][k], W1[k * FF + f], acc);
        h1[b][f] = fmaxf(acc, 0.f);
    }
    __syncthreads();
#pragma unroll
    for (int b = 0; b < BB; ++b) {
        float acc = b2[f];
#pragma unroll
        for (int k = 0; k < FF; ++k) acc = fmaf(h1[b][k], W2[k * FF + f], acc);
        hv[b][f] = fmaxf(acc, 0.f);
    }
    __syncthreads();
#pragma unroll
    for (int b = 0; b < BB; ++b) {
        float p = hv[b][f] * W3[f];
#pragma unroll
        for (int off = 32; off > 0; off >>= 1) p += __shfl_down(p, off);
        if (f == 0) out[b] = p + b3[0];
    }
}

// ---------------------------------------------------------------------------
extern "C" void kernel_launch(void* const* d_in, const int* in_sizes, int n_in,
                              void* d_out, int out_size, void* d_ws, size_t ws_size,
                              hipStream_t stream)
{
    const int*   A      = (const int*)d_in[0];
    const float* x      = (const float*)d_in[1];
    float*       e_attr = (float*)d_in[2];  // in-place (harness restores)

    const float* We0 = (const float*)d_in[3];
    const float* be0 = (const float*)d_in[4];
    const float* Wn0 = (const float*)d_in[5];
    const float* bn0 = (const float*)d_in[6];
    const float* We1 = (const float*)d_in[7];
    const float* be1 = (const float*)d_in[8];
    const float* We2 = (const float*)d_in[11];
    const float* be2 = (const float*)d_in[12];
    const float* W1 = (const float*)d_in[15];
    const float* b1 = (const float*)d_in[16];
    const float* W2 = (const float*)d_in[17];
    const float* b2 = (const float*)d_in[18];
    const float* W3 = (const float*)d_in[19];
    const float* b3 = (const float*)d_in[20];
    float* out = (float*)d_out;
    (void)in_sizes; (void)n_in; (void)out_size; (void)ws_size;

    const int R = BB * NN;   // 2048 rows
    float* P1  = (float*)d_ws;        // also P0
    float* Q1  = P1 + R * FF;         // also Q0
    float* P2  = Q1 + R * FF;
    float* Q2  = P2 + R * FF;
    float* agg = Q2 + R * FF;
    float* v   = agg + R * FF;        // 512 floats
    u16*  wimg = (u16*)(v + 512);     // 3 layers x (4096 hi + 4096 lo) u16

    u16* e1 = (u16*)e_attr;  // bf16 e1, row stride 128 u16 (first half of rows)

    pq_kernel<<<R / 4, 256, 0, stream>>>(x, We0, be0, P1, Q1, agg,
                                         We0, We1, We2, wimg);
    edge0_kernel<<<2 * R / T0, 256, 0, stream>>>(e_attr, e1, wimg, P1, Q1, A, agg);
    nodepq_kernel<<<R / 4, 256, 0, stream>>>(x, agg, A, Wn0, bn0, We1, be1,
                                             We2, be2, P1, Q1, P2, Q2, v);
    edge12_kernel<<<2 * R / T12, 256, 0, stream>>>(e1, wimg + 8192, wimg + 16384,
                                                   P1, Q1, P2, Q2, A, v);
    head_kernel<<<1, 64, 0, stream>>>(v, W1, b1, W2, b2, W3, b3, out);
}

// Round 6
// 365.946 us; speedup vs baseline: 1.3278x; 1.3278x over previous
//
#include <hip/hip_runtime.h>

#define BB 8
#define NN 256
#define FF 64

typedef float f32x4 __attribute__((ext_vector_type(4)));
typedef short s16x8 __attribute__((ext_vector_type(8)));
typedef unsigned short u16;

#define MFMA_BF16(a, b, c) __builtin_amdgcn_mfma_f32_16x16x32_bf16(a, b, c, 0, 0, 0)

__device__ inline u16 f2bf(float x) {
    unsigned u = __float_as_uint(x);
    u += 0x7FFFu + ((u >> 16) & 1u);
    return (u16)(u >> 16);
}
__device__ inline float bf2f(u16 h) { return __uint_as_float(((unsigned)h) << 16); }

__device__ inline s16x8 cvt8(f32x4 a, f32x4 b) {
    s16x8 r;
    r[0] = (short)f2bf(a[0]); r[1] = (short)f2bf(a[1]);
    r[2] = (short)f2bf(a[2]); r[3] = (short)f2bf(a[3]);
    r[4] = (short)f2bf(b[0]); r[5] = (short)f2bf(b[1]);
    r[6] = (short)f2bf(b[2]); r[7] = (short)f2bf(b[3]);
    return r;
}

// ---------------------------------------------------------------------------
// pq (+ fused wprep): P[r]=be+x[r]@We[0:64], Q[r]=x[r]@We[64:128]; zero agg.
// Blocks 0..2 build the W-MFMA images (transposed [f][k], XOR-swizzled
// k-chunks, hi/lo bf16 split).
// ---------------------------------------------------------------------------
__global__ __launch_bounds__(256) void pq_kernel(
    const float* __restrict__ x, const float* __restrict__ We,
    const float* __restrict__ be, float* __restrict__ P, float* __restrict__ Q,
    float* __restrict__ agg,
    const float* __restrict__ We0, const float* __restrict__ We1,
    const float* __restrict__ We2, u16* __restrict__ wimg)
{
    const int rl = threadIdx.x >> 6, f = threadIdx.x & 63;
    const int r = blockIdx.x * 4 + rl;
    __shared__ float xs[4][FF];
    xs[rl][f] = x[r * FF + f];
    agg[r * FF + f] = 0.f;

    if (blockIdx.x < 3) {
        const float* src =
            (blockIdx.x == 0 ? We0 : (blockIdx.x == 1 ? We1 : We2)) + 2 * FF * FF;
        u16* hi = wimg + blockIdx.x * 8192;
        u16* lo = hi + 4096;
        for (int idx = threadIdx.x; idx < 4096; idx += 256) {
            const int ff = idx >> 6, rem = idx & 63, cs = rem >> 3, j = rem & 7;
            const int k = ((cs ^ (ff & 7)) << 3) | j;
            const float wv = src[k * FF + ff];
            const u16 h = f2bf(wv);
            hi[idx] = h;
            lo[idx] = f2bf(wv - bf2f(h));
        }
    }
    __syncthreads();
    float p = be[f], q = 0.f;
#pragma unroll
    for (int k = 0; k < FF; ++k) {
        const float xv = xs[rl][k];
        p = fmaf(xv, We[k * FF + f], p);
        q = fmaf(xv, We[(FF + k) * FF + f], q);
    }
    P[r * FF + f] = p;
    Q[r * FF + f] = q;
}

// ---------------------------------------------------------------------------
// edge0 (MFMA, transposed: D[f][e] = Wc^T E^T). One 128-edge tile per block.
// Lane holds (D-layout) f = 16ft+4quad+r, e = 32w+16et+l15.
// Writes e1 as packed bf16 into the first half of each fp32 e_attr row.
// ---------------------------------------------------------------------------
__global__ __launch_bounds__(256) void edge0_kernel(
    const float* __restrict__ e_in, u16* __restrict__ e1_out,
    const u16* __restrict__ wimg, const float* __restrict__ P,
    const float* __restrict__ Q, const int* __restrict__ Adj,
    float* __restrict__ agg)
{
    __shared__ u16 Wh[4096], Wl[4096];
    const int tid = threadIdx.x;
#pragma unroll
    for (int m = 0; m < 2; ++m) {
        ((uint4*)Wh)[tid + 256 * m] = ((const uint4*)wimg)[tid + 256 * m];
        ((uint4*)Wl)[tid + 256 * m] = ((const uint4*)(wimg + 4096))[tid + 256 * m];
    }
    __syncthreads();

    const int w = tid >> 6, lane = tid & 63;
    const int quad = lane >> 4, l15 = lane & 15, l7 = lane & 7;
    const int e0 = 32 * w + l15;

    const int bt = blockIdx.x;
    const int bi = bt >> 1, b = bi >> 8;
    const int j0 = (bt & 1) << 7;

    // E B-frags: E[e][k = ks*32 + quad*8 + j], fp32 -> bf16
    f32x4 ef[2][2][2];
    const float* erow = e_in + ((size_t)bi * NN + j0) * FF;
#pragma unroll
    for (int ks = 0; ks < 2; ++ks)
#pragma unroll
        for (int et = 0; et < 2; ++et) {
            const float* p = erow + (size_t)(e0 + 16 * et) * FF + ks * 32 + quad * 8;
            ef[ks][et][0] = *(const f32x4*)p;
            ef[ks][et][1] = *(const f32x4*)(p + 4);
        }

    float av[2];
#pragma unroll
    for (int et = 0; et < 2; ++et)
        av[et] = (float)Adj[bi * NN + j0 + e0 + 16 * et];
    f32x4 pv[4];
#pragma unroll
    for (int ft = 0; ft < 4; ++ft)
        pv[ft] = *(const f32x4*)(P + bi * FF + ft * 16 + quad * 4);
    f32x4 qv[2][4];
    const float* Qb = Q + ((size_t)b * NN + j0) * FF;
#pragma unroll
    for (int et = 0; et < 2; ++et)
#pragma unroll
        for (int ft = 0; ft < 4; ++ft)
            qv[et][ft] = *(const f32x4*)(Qb + (size_t)(e0 + 16 * et) * FF +
                                         ft * 16 + quad * 4);

    f32x4 acc[2][4];
#pragma unroll
    for (int et = 0; et < 2; ++et)
#pragma unroll
        for (int ft = 0; ft < 4; ++ft) acc[et][ft] = (f32x4){0.f, 0.f, 0.f, 0.f};

#pragma unroll
    for (int ks = 0; ks < 2; ++ks) {
        s16x8 efr[2];
#pragma unroll
        for (int et = 0; et < 2; ++et) efr[et] = cvt8(ef[ks][et][0], ef[ks][et][1]);
#pragma unroll
        for (int ft = 0; ft < 4; ++ft) {
            const int off = (16 * ft + l15) * 64 + (((ks * 4 + quad) ^ l7) << 3);
            const s16x8 ah = *(const s16x8*)&Wh[off];
            const s16x8 al = *(const s16x8*)&Wl[off];
#pragma unroll
            for (int et = 0; et < 2; ++et) {
                acc[et][ft] = MFMA_BF16(ah, efr[et], acc[et][ft]);
                acc[et][ft] = MFMA_BF16(al, efr[et], acc[et][ft]);
            }
        }
    }

    // epilogue: relu(acc + P[f] + Q[e][f]) * A[e]; store bf16x4; row-sums
    float sac[4][4];
#pragma unroll
    for (int ft = 0; ft < 4; ++ft)
#pragma unroll
        for (int r = 0; r < 4; ++r) sac[ft][r] = 0.f;
#pragma unroll
    for (int et = 0; et < 2; ++et) {
        const size_t erow_g = (size_t)bi * NN + j0 + e0 + 16 * et;
#pragma unroll
        for (int ft = 0; ft < 4; ++ft) {
            float rr[4];
#pragma unroll
            for (int r = 0; r < 4; ++r) {
                const float val = acc[et][ft][r] + pv[ft][r] + qv[et][ft][r];
                rr[r] = fmaxf(val, 0.f) * av[et];
                sac[ft][r] += rr[r];
            }
            ushort4 st;
            st.x = f2bf(rr[0]); st.y = f2bf(rr[1]);
            st.z = f2bf(rr[2]); st.w = f2bf(rr[3]);
            *(ushort4*)(e1_out + erow_g * 128 + ft * 16 + quad * 4) = st;
        }
    }
#pragma unroll
    for (int ft = 0; ft < 4; ++ft)
#pragma unroll
        for (int r = 0; r < 4; ++r) {
            float s = sac[ft][r];
            s += __shfl_xor(s, 1, 16);
            s += __shfl_xor(s, 2, 16);
            s += __shfl_xor(s, 4, 16);
            s += __shfl_xor(s, 8, 16);
            if (l15 == 0)
                atomicAdd(&agg[bi * FF + ft * 16 + quad * 4 + r], s);
        }
}

// ---------------------------------------------------------------------------
// fused node-update + deg + pq(1,2) + zero v.
// ---------------------------------------------------------------------------
__global__ __launch_bounds__(256) void nodepq_kernel(
    const float* __restrict__ x, const float* __restrict__ agg,
    const int* __restrict__ A,
    const float* __restrict__ Wn, const float* __restrict__ bn,
    const float* __restrict__ We1, const float* __restrict__ be1,
    const float* __restrict__ We2, const float* __restrict__ be2,
    float* __restrict__ P1, float* __restrict__ Q1,
    float* __restrict__ P2, float* __restrict__ Q2, float* __restrict__ v)
{
    const int rl = threadIdx.x >> 6, f = threadIdx.x & 63;
    const int r = blockIdx.x * 4 + rl;
    __shared__ float s[4][2 * FF];
    __shared__ float x1s[4][FF];

    float da = (float)A[r * NN + f] + (float)A[r * NN + f + 64] +
               (float)A[r * NN + f + 128] + (float)A[r * NN + f + 192];
#pragma unroll
    for (int off = 32; off > 0; off >>= 1) da += __shfl_down(da, off, 64);
    const float deg = fmaxf(__shfl(da, 0, 64), 1.0f);

    s[rl][f]      = x[r * FF + f];
    s[rl][FF + f] = agg[r * FF + f] / deg;
    if (blockIdx.x == 0) {
        v[threadIdx.x] = 0.f;
        v[256 + threadIdx.x] = 0.f;
    }
    __syncthreads();
    float a = bn[f];
#pragma unroll
    for (int k = 0; k < 2 * FF; ++k) a = fmaf(s[rl][k], Wn[k * FF + f], a);
    x1s[rl][f] = fmaxf(a, 0.f);
    __syncthreads();
    float p1 = be1[f], q1 = 0.f, p2 = be2[f], q2 = 0.f;
#pragma unroll
    for (int k = 0; k < FF; ++k) {
        const float xv = x1s[rl][k];
        p1 = fmaf(xv, We1[k * FF + f], p1);
        q1 = fmaf(xv, We1[(FF + k) * FF + f], q1);
        p2 = fmaf(xv, We2[k * FF + f], p2);
        q2 = fmaf(xv, We2[(FF + k) * FF + f], q2);
    }
    P1[r * FF + f] = p1;  Q1[r * FF + f] = q1;
    P2[r * FF + f] = p2;  Q2[r * FF + f] = q2;
}

// ---------------------------------------------------------------------------
// fused layers 1+2 (MFMA, transposed). One tile per block. e2 round-trips
// through wave-private XOR-swizzled LDS (stride 64 u16 -> balanced banks);
// e3 reduced block-wide then one atomicAdd per f to v.
// ---------------------------------------------------------------------------
__global__ __launch_bounds__(256) void edge12_kernel(
    const u16* __restrict__ e1,
    const u16* __restrict__ w1img, const u16* __restrict__ w2img,
    const float* __restrict__ P1, const float* __restrict__ Q1,
    const float* __restrict__ P2, const float* __restrict__ Q2,
    const int* __restrict__ Adj, float* __restrict__ v)
{
    __shared__ u16 W1h[4096], W1l[4096], W2h[4096], W2l[4096];
    __shared__ u16 E2[4][32 * 64];
    __shared__ float red[FF];
    const int tid = threadIdx.x;
#pragma unroll
    for (int m = 0; m < 2; ++m) {
        ((uint4*)W1h)[tid + 256 * m] = ((const uint4*)w1img)[tid + 256 * m];
        ((uint4*)W1l)[tid + 256 * m] = ((const uint4*)(w1img + 4096))[tid + 256 * m];
        ((uint4*)W2h)[tid + 256 * m] = ((const uint4*)w2img)[tid + 256 * m];
        ((uint4*)W2l)[tid + 256 * m] = ((const uint4*)(w2img + 4096))[tid + 256 * m];
    }
    if (tid < FF) red[tid] = 0.f;
    __syncthreads();

    const int w = tid >> 6, lane = tid & 63;
    const int quad = lane >> 4, l15 = lane & 15, l7 = lane & 7;
    const int e0 = 32 * w + l15;
    u16* E2w = E2[w];

    const int bt = blockIdx.x;
    const int bi = bt >> 1, b = bi >> 8;
    const int j0 = (bt & 1) << 7;

    // e1 B-frags (packed bf16)
    s16x8 bfr[2][2];
#pragma unroll
    for (int ks = 0; ks < 2; ++ks)
#pragma unroll
        for (int et = 0; et < 2; ++et)
            bfr[ks][et] = *(const s16x8*)(e1 +
                ((size_t)bi * NN + j0 + e0 + 16 * et) * 128 + ks * 32 + quad * 8);

    float av[2];
#pragma unroll
    for (int et = 0; et < 2; ++et)
        av[et] = (float)Adj[bi * NN + j0 + e0 + 16 * et];
    f32x4 pv[4];
#pragma unroll
    for (int ft = 0; ft < 4; ++ft)
        pv[ft] = *(const f32x4*)(P1 + bi * FF + ft * 16 + quad * 4);
    f32x4 qv[2][4];
    const float* Q1b = Q1 + ((size_t)b * NN + j0) * FF;
#pragma unroll
    for (int et = 0; et < 2; ++et)
#pragma unroll
        for (int ft = 0; ft < 4; ++ft)
            qv[et][ft] = *(const f32x4*)(Q1b + (size_t)(e0 + 16 * et) * FF +
                                         ft * 16 + quad * 4);

    // ---------------- GEMM1 ----------------
    f32x4 acc[2][4];
#pragma unroll
    for (int et = 0; et < 2; ++et)
#pragma unroll
        for (int ft = 0; ft < 4; ++ft) acc[et][ft] = (f32x4){0.f, 0.f, 0.f, 0.f};
#pragma unroll
    for (int ks = 0; ks < 2; ++ks)
#pragma unroll
        for (int ft = 0; ft < 4; ++ft) {
            const int off = (16 * ft + l15) * 64 + (((ks * 4 + quad) ^ l7) << 3);
            const s16x8 ah = *(const s16x8*)&W1h[off];
            const s16x8 al = *(const s16x8*)&W1l[off];
#pragma unroll
            for (int et = 0; et < 2; ++et) {
                acc[et][ft] = MFMA_BF16(ah, bfr[ks][et], acc[et][ft]);
                acc[et][ft] = MFMA_BF16(al, bfr[ks][et], acc[et][ft]);
            }
        }

    // epilogue 1 -> wave-private E2 image [e_local][f], stride 64, XOR chunks
#pragma unroll
    for (int et = 0; et < 2; ++et) {
        const int erow_l = (16 * et + l15) * 64;
#pragma unroll
        for (int ft = 0; ft < 4; ++ft) {
            float rr[4];
#pragma unroll
            for (int r = 0; r < 4; ++r) {
                const float val = acc[et][ft][r] + pv[ft][r] + qv[et][ft][r];
                rr[r] = fmaxf(val, 0.f) * av[et];
            }
            ushort4 st;
            st.x = f2bf(rr[0]); st.y = f2bf(rr[1]);
            st.z = f2bf(rr[2]); st.w = f2bf(rr[3]);
            const int c  = 2 * ft + (quad >> 1);          // f-chunk
            const int cs = c ^ l7;                        // swizzled slot
            *(ushort4*)&E2w[erow_l + cs * 8 + (quad & 1) * 4] = st;
        }
    }

    // P2/Q2 for epilogue 2
#pragma unroll
    for (int ft = 0; ft < 4; ++ft)
        pv[ft] = *(const f32x4*)(P2 + bi * FF + ft * 16 + quad * 4);
    const float* Q2b = Q2 + ((size_t)b * NN + j0) * FF;
#pragma unroll
    for (int et = 0; et < 2; ++et)
#pragma unroll
        for (int ft = 0; ft < 4; ++ft)
            qv[et][ft] = *(const f32x4*)(Q2b + (size_t)(e0 + 16 * et) * FF +
                                         ft * 16 + quad * 4);

    // ---------------- GEMM2 (wave-private E2, no barrier) ----------------
#pragma unroll
    for (int et = 0; et < 2; ++et)
#pragma unroll
        for (int ft = 0; ft < 4; ++ft) acc[et][ft] = (f32x4){0.f, 0.f, 0.f, 0.f};
#pragma unroll
    for (int ks = 0; ks < 2; ++ks) {
        s16x8 e2f[2];
#pragma unroll
        for (int et = 0; et < 2; ++et) {
            const int cs = (ks * 4 + quad) ^ l7;          // k-chunk swizzled
            e2f[et] = *(const s16x8*)&E2w[(16 * et + l15) * 64 + cs * 8];
        }
#pragma unroll
        for (int ft = 0; ft < 4; ++ft) {
            const int off = (16 * ft + l15) * 64 + (((ks * 4 + quad) ^ l7) << 3);
            const s16x8 ah = *(const s16x8*)&W2h[off];
            const s16x8 al = *(const s16x8*)&W2l[off];
#pragma unroll
            for (int et = 0; et < 2; ++et) {
                acc[et][ft] = MFMA_BF16(ah, e2f[et], acc[et][ft]);
                acc[et][ft] = MFMA_BF16(al, e2f[et], acc[et][ft]);
            }
        }
    }

    // epilogue 2: psum over own 32 edges, reduce over l15, LDS-reduce, flush
    float psum[4][4];
#pragma unroll
    for (int ft = 0; ft < 4; ++ft)
#pragma unroll
        for (int r = 0; r < 4; ++r) psum[ft][r] = 0.f;
#pragma unroll
    for (int et = 0; et < 2; ++et)
#pragma unroll
        for (int ft = 0; ft < 4; ++ft)
#pragma unroll
            for (int r = 0; r < 4; ++r) {
                const float val = acc[et][ft][r] + pv[ft][r] + qv[et][ft][r];
                psum[ft][r] += fmaxf(val, 0.f) * av[et];
            }
#pragma unroll
    for (int ft = 0; ft < 4; ++ft)
#pragma unroll
        for (int r = 0; r < 4; ++r) {
            float s = psum[ft][r];
            s += __shfl_xor(s, 1, 16);
            s += __shfl_xor(s, 2, 16);
            s += __shfl_xor(s, 4, 16);
            s += __shfl_xor(s, 8, 16);
            if (l15 == 0) atomicAdd(&red[ft * 16 + quad * 4 + r], s);
        }
    __syncthreads();
    if (tid < FF) atomicAdd(&v[b * FF + tid], red[tid]);
}

// ---------------------------------------------------------------------------
// head: v/65536 -> relu(@W1+b1) -> relu(@W2+b2) -> @W3+b3
// ---------------------------------------------------------------------------
__global__ __launch_bounds__(64) void head_kernel(
    const float* __restrict__ vsum, const float* __restrict__ W1,
    const float* __restrict__ b1, const float* __restrict__ W2,
    const float* __restrict__ b2, const float* __restrict__ W3,
    const float* __restrict__ b3, float* __restrict__ out)
{
    const int f = threadIdx.x;
    __shared__ float hv[BB][FF];
    __shared__ float h1[BB][FF];
#pragma unroll
    for (int b = 0; b < BB; ++b) hv[b][f] = vsum[b * FF + f] * (1.0f / 65536.0f);
    __syncthreads();
#pragma unroll
    for (int b = 0; b < BB; ++b) {
        float acc = b1[f];
#pragma unroll
        for (int k = 0; k < FF; ++k) acc = fmaf(hv[b][k], W1[k * FF + f], acc);
        h1[b][f] = fmaxf(acc, 0.f);
    }
    __syncthreads();
#pragma unroll
    for (int b = 0; b < BB; ++b) {
        float acc = b2[f];
#pragma unroll
        for (int k = 0; k < FF; ++k) acc = fmaf(h1[b][k], W2[k * FF + f], acc);
        hv[b][f] = fmaxf(acc, 0.f);
    }
    __syncthreads();
#pragma unroll
    for (int b = 0; b < BB; ++b) {
        float p = hv[b][f] * W3[f];
#pragma unroll
        for (int off = 32; off > 0; off >>= 1) p += __shfl_down(p, off);
        if (f == 0) out[b] = p + b3[0];
    }
}

// ---------------------------------------------------------------------------
extern "C" void kernel_launch(void* const* d_in, const int* in_sizes, int n_in,
                              void* d_out, int out_size, void* d_ws, size_t ws_size,
                              hipStream_t stream)
{
    const int*   A      = (const int*)d_in[0];
    const float* x      = (const float*)d_in[1];
    float*       e_attr = (float*)d_in[2];  // in-place (harness restores)

    const float* We0 = (const float*)d_in[3];
    const float* be0 = (const float*)d_in[4];
    const float* Wn0 = (const float*)d_in[5];
    const float* bn0 = (const float*)d_in[6];
    const float* We1 = (const float*)d_in[7];
    const float* be1 = (const float*)d_in[8];
    const float* We2 = (const float*)d_in[11];
    const float* be2 = (const float*)d_in[12];
    const float* W1 = (const float*)d_in[15];
    const float* b1 = (const float*)d_in[16];
    const float* W2 = (const float*)d_in[17];
    const float* b2 = (const float*)d_in[18];
    const float* W3 = (const float*)d_in[19];
    const float* b3 = (const float*)d_in[20];
    float* out = (float*)d_out;
    (void)in_sizes; (void)n_in; (void)out_size; (void)ws_size;

    const int R = BB * NN;   // 2048 rows
    float* P1  = (float*)d_ws;        // also P0
    float* Q1  = P1 + R * FF;         // also Q0
    float* P2  = Q1 + R * FF;
    float* Q2  = P2 + R * FF;
    float* agg = Q2 + R * FF;
    float* v   = agg + R * FF;        // 512 floats
    u16*  wimg = (u16*)(v + 512);     // 3 layers x (4096 hi + 4096 lo) u16

    u16* e1 = (u16*)e_attr;  // bf16 e1, row stride 128 u16 (first half of rows)

    pq_kernel<<<R / 4, 256, 0, stream>>>(x, We0, be0, P1, Q1, agg,
                                         We0, We1, We2, wimg);
    edge0_kernel<<<2 * R, 256, 0, stream>>>(e_attr, e1, wimg, P1, Q1, A, agg);
    nodepq_kernel<<<R / 4, 256, 0, stream>>>(x, agg, A, Wn0, bn0, We1, be1,
                                             We2, be2, P1, Q1, P2, Q2, v);
    edge12_kernel<<<2 * R, 256, 0, stream>>>(e1, wimg + 8192, wimg + 16384,
                                             P1, Q1, P2, Q2, A, v);
    head_kernel<<<1, 64, 0, stream>>>(v, W1, b1, W2, b2, W3, b3, out);
}